// Round 1
// baseline (2004.092 us; speedup 1.0000x reference)
//
#include <hip/hip_runtime.h>

#define TT   365
#define BTOT 2048
#define DIN  32
#define SIN  27
#define HD   256
#define G3   768
#define BBLK 16
#define NW   16
#define BLOCK (NW*64)
#define NT   3           // gate-column tiles per wave (48 cols)
#define GST  772         // gates LDS row stride in floats (768 pads to avoid bank alias)

typedef float  f32x4  __attribute__((ext_vector_type(4)));
typedef short  bf16x8 __attribute__((ext_vector_type(8)));

__device__ __forceinline__ unsigned short f2bf(float f) {
  unsigned u = __builtin_bit_cast(unsigned, f);
  u += 0x7fffu + ((u >> 16) & 1u);          // RNE to bf16
  return (unsigned short)(u >> 16);
}
__device__ __forceinline__ float fsig(float x) {
  float e = __builtin_amdgcn_exp2f(x * -1.442695040888963f);
  return __builtin_amdgcn_rcpf(1.0f + e);
}
__device__ __forceinline__ float ftanh(float x) {
  float e = __builtin_amdgcn_exp2f(x * 2.885390081777927f); // exp2(2x*log2e) = e^{2x}
  return 1.0f - 2.0f * __builtin_amdgcn_rcpf(1.0f + e);
}

__global__ void prep_kernel(const float* __restrict__ whh, const float* __restrict__ wih,
                            unsigned short* __restrict__ whh_bf,
                            unsigned short* __restrict__ wih_bf) {
  int stride = gridDim.x * blockDim.x;
  int i0 = blockIdx.x * blockDim.x + threadIdx.x;
  for (int i = i0; i < G3 * HD;  i += stride) whh_bf[i] = f2bf(whh[i]);
  for (int i = i0; i < G3 * DIN; i += stride) wih_bf[i] = f2bf(wih[i]);
}

// One persistent block per 16 batch rows. Recurrence over T inside the kernel.
// gates = h @ Whh^T + x @ Wih^T (+bias in elementwise phase), MFMA bf16, fp32 acc.
__global__ void __launch_bounds__(BLOCK)
ealstm_kernel(const float* __restrict__ x_dd, const float* __restrict__ x_s,
              const float* __restrict__ bias, const float* __restrict__ w_in,
              const float* __restrict__ b_in, const float* __restrict__ w_dense,
              const float* __restrict__ b_dense,
              const unsigned short* __restrict__ whh_bf,
              const unsigned short* __restrict__ wih_bf,
              float* __restrict__ out) {
  __shared__ float gates[16][GST];                 // 49,408 B (pre-activation, fp32)
  __shared__ unsigned short hlds[16 * HD];         // 8,192 B  (h, bf16, XOR-swizzled)
  __shared__ unsigned short xlds[2][16 * DIN];     // 2,048 B  (x_t, bf16, double-buffered)

  const int tid  = threadIdx.x;
  const int b0   = blockIdx.x * BBLK;
  const int wave = tid >> 6;
  const int lane = tid & 63;
  const int m    = lane & 15;                      // MFMA row/col-in-16 index
  const int q    = lane >> 4;                      // k-group 0..3
  const int n0w  = wave * (G3 / NW);               // this wave's first gate column (48/wave)

  for (int i = tid; i < 16 * HD; i += BLOCK) hlds[i] = 0;   // h0 = 0

  // stage x for t=0
  if (tid < BBLK * DIN) {
    int bb = tid >> 5, d = tid & 31;
    xlds[0][bb * DIN + d] = f2bf(x_dd[(size_t)(b0 + bb) * DIN + d]);
  }

  // per-thread elementwise state: fixed j = tid&255, four batch rows b = (tid>>8)+4s
  const int j = tid & 255;
  const float bf_ = bias[j], bg_ = bias[HD + j], bo_ = bias[2 * HD + j];
  const float wdj = w_dense[j];
  float cst[4], ig[4];
  #pragma unroll
  for (int s = 0; s < 4; ++s) {
    int b = (tid >> 8) + s * 4;
    float a = b_in[j];
    const float* xr = x_s + (size_t)(b0 + b) * SIN;
    const float* wr = w_in + (size_t)j * SIN;
    #pragma unroll
    for (int ss = 0; ss < SIN; ++ss) a += xr[ss] * wr[ss];
    ig[s] = fsig(a);                 // static input gate i (computed once)
    cst[s] = 0.0f;                   // c0 = 0
  }
  __syncthreads();

  // h A-fragment addressing: element (m, k) lives at byte (m*512 + 2k) ^ ((m&7)<<4)
  const int sw    = (m & 7) << 4;
  const int abase = m * (HD * 2) + q * 16;
  const char* hbytes = (const char*)hlds;
  int cur = 0;

  for (int t = 0; t < TT; ++t) {
    // prefetch next timestep's x into registers (hidden under MFMA phase)
    float xnext = 0.0f;
    int bb = 0, d = 0;
    if (tid < BBLK * DIN) {
      bb = tid >> 5; d = tid & 31;
      int tn = (t + 1 < TT) ? (t + 1) : t;
      xnext = x_dd[((size_t)tn * BTOT + b0 + bb) * DIN + d];
    }

    // ---- MFMA phase: gates(16 x 768) = h @ Whh^T + x @ Wih^T ----
    f32x4 acc[NT];
    #pragma unroll
    for (int n = 0; n < NT; ++n) {
      #pragma unroll
      for (int r = 0; r < 4; ++r) acc[n][r] = 0.0f;
    }

    #pragma unroll
    for (int kk = 0; kk < 8; ++kk) {                       // K over H=256
      bf16x8 af = *(const bf16x8*)(hbytes + ((abase + kk * 64) ^ sw));
      const unsigned short* wb = whh_bf + (size_t)(n0w + m) * HD + kk * 32 + q * 8;
      #pragma unroll
      for (int n = 0; n < NT; ++n) {
        bf16x8 wf = *(const bf16x8*)(wb + n * 16 * HD);
        acc[n] = __builtin_amdgcn_mfma_f32_16x16x32_bf16(af, wf, acc[n], 0, 0, 0);
      }
    }
    {                                                      // K over D=32 (input proj)
      bf16x8 af = *(const bf16x8*)((const char*)xlds[cur] + m * (DIN * 2) + q * 16);
      const unsigned short* wb = wih_bf + (size_t)(n0w + m) * DIN + q * 8;
      #pragma unroll
      for (int n = 0; n < NT; ++n) {
        bf16x8 wf = *(const bf16x8*)(wb + n * 16 * DIN);
        acc[n] = __builtin_amdgcn_mfma_f32_16x16x32_bf16(af, wf, acc[n], 0, 0, 0);
      }
    }

    // D layout: col = lane&15, row = (lane>>4)*4 + r
    #pragma unroll
    for (int n = 0; n < NT; ++n) {
      #pragma unroll
      for (int r = 0; r < 4; ++r)
        gates[q * 4 + r][n0w + n * 16 + m] = acc[n][r];
    }
    __syncthreads();

    // ---- elementwise phase: f,g,o -> c,h ----
    #pragma unroll
    for (int s = 0; s < 4; ++s) {
      int b = (tid >> 8) + s * 4;
      float f = fsig (gates[b][j]          + bf_);
      float g = ftanh(gates[b][HD + j]     + bg_);
      float o = fsig (gates[b][2 * HD + j] + bo_);
      float c = f * cst[s] + ig[s] * g;
      cst[s] = c;
      float h = o * ftanh(c);
      int off = (b * (HD * 2) + j * 2) ^ ((b & 7) << 4);   // swizzled bf16 h store
      *(unsigned short*)((char*)hlds + off) = f2bf(h);
      if (t == TT - 1) gates[b][j] = h * wdj;              // overwrite consumed f-slot
    }
    if (tid < BBLK * DIN) xlds[cur ^ 1][bb * DIN + d] = f2bf(xnext);
    __syncthreads();
    cur ^= 1;
  }

  // ---- output: out[b] = sum_j h[b][j]*w_dense[j] + b_dense ----
  if (tid < 128) {
    int b = tid >> 3, ch = tid & 7;
    float sum = 0.0f;
    #pragma unroll
    for (int jj = 0; jj < 32; ++jj) sum += gates[b][ch * 32 + jj];
    sum += __shfl_xor(sum, 1, 64);
    sum += __shfl_xor(sum, 2, 64);
    sum += __shfl_xor(sum, 4, 64);
    if (ch == 0) out[b0 + b] = sum + b_dense[0];
  }
}

extern "C" void kernel_launch(void* const* d_in, const int* in_sizes, int n_in,
                              void* d_out, int out_size, void* d_ws, size_t ws_size,
                              hipStream_t stream) {
  (void)in_sizes; (void)n_in; (void)out_size; (void)ws_size;
  const float* x_dd = (const float*)d_in[0];
  const float* x_s  = (const float*)d_in[1];
  const float* wih  = (const float*)d_in[2];
  const float* whh  = (const float*)d_in[3];
  const float* bias = (const float*)d_in[4];
  const float* w_in = (const float*)d_in[5];
  const float* b_in = (const float*)d_in[6];
  const float* w_d  = (const float*)d_in[7];
  const float* b_d  = (const float*)d_in[8];
  float* out = (float*)d_out;

  unsigned short* whh_bf = (unsigned short*)d_ws;            // 768*256 bf16
  unsigned short* wih_bf = whh_bf + G3 * HD;                 // 768*32  bf16

  prep_kernel<<<128, 256, 0, stream>>>(whh, wih, whh_bf, wih_bf);
  ealstm_kernel<<<BTOT / BBLK, BLOCK, 0, stream>>>(
      x_dd, x_s, bias, w_in, b_in, w_d, b_d, whh_bf, wih_bf, out);
}

// Round 2
// 661.840 us; speedup vs baseline: 3.0281x; 3.0281x over previous
//
#include <hip/hip_runtime.h>

#define TT   365
#define BTOT 2048
#define DIN  32
#define SIN  27
#define HD   256
#define G3   768
#define BBLK 8
#define BLOCK 512
#define ZBUF 4608   // bytes per z buffer: 9 kk * 4 q * 8 rows * 16B

typedef float  f32x4  __attribute__((ext_vector_type(4)));
typedef short  bf16x8 __attribute__((ext_vector_type(8)));

__device__ __forceinline__ unsigned short f2bf(float f) {
  unsigned u = __builtin_bit_cast(unsigned, f);
  u += 0x7fffu + ((u >> 16) & 1u);          // RNE to bf16
  return (unsigned short)(u >> 16);
}
__device__ __forceinline__ float bf2f(unsigned short u) {
  unsigned v = ((unsigned)u) << 16;
  return __builtin_bit_cast(float, v);
}
__device__ __forceinline__ float fsig(float x) {
  float e = __builtin_amdgcn_exp2f(x * -1.442695040888963f);
  return __builtin_amdgcn_rcpf(1.0f + e);
}
__device__ __forceinline__ float ftanh(float x) {
  float e = __builtin_amdgcn_exp2f(x * 2.885390081777927f); // e^{2x}
  return 1.0f - 2.0f * __builtin_amdgcn_rcpf(1.0f + e);
}

__global__ void prep_kernel(const float* __restrict__ whh, const float* __restrict__ wih,
                            unsigned short* __restrict__ whh_bf,
                            unsigned short* __restrict__ wih_bf) {
  int stride = gridDim.x * blockDim.x;
  int i0 = blockIdx.x * blockDim.x + threadIdx.x;
  for (int i = i0; i < G3 * HD;  i += stride) whh_bf[i] = f2bf(whh[i]);
  for (int i = i0; i < G3 * DIN; i += stride) wih_bf[i] = f2bf(wih[i]);
}

// Persistent block per 8 batch rows; full recurrence in-kernel.
// z = [h(256); x(32)] in LDS frag layout: frag(kk,q,row) 16B at ((kk*4+q)*8+row)*16.
// Whh resident in VGPRs (B-frag layout), Wih in LDS (swizzled). One barrier/step.
__global__ void __launch_bounds__(BLOCK, 2)
ealstm_kernel(const float* __restrict__ x_dd, const float* __restrict__ x_s,
              const float* __restrict__ bias, const float* __restrict__ w_in,
              const float* __restrict__ b_in, const float* __restrict__ w_dense,
              const float* __restrict__ b_dense,
              const unsigned short* __restrict__ whh_bf,
              const unsigned short* __restrict__ wih_bf,
              float* __restrict__ out) {
  __shared__ __attribute__((aligned(16))) char zb[2 * ZBUF];
  __shared__ __attribute__((aligned(16))) char wih_l[G3 * DIN * 2];

  const int tid  = threadIdx.x;
  const int b0   = blockIdx.x * BBLK;
  const int w    = tid >> 6;          // wave 0..7
  const int lane = tid & 63;
  const int m    = lane & 15;         // MFMA col-in-16 (and A-row)
  const int q    = lane >> 4;         // k-group 0..3
  const int qh   = (q >> 1);          // 0: col group w, 1: col group w+8
  const int j    = (w + qh * 8) * 16 + m;    // this lane's h/gate column

  // ---- stage Wih into LDS (swizzled: slot varies with m across octets) ----
  for (int i = tid; i < (G3 * DIN) / 8; i += BLOCK) {
    int g = i >> 2, qq = i & 3;
    bf16x8 v = *(const bf16x8*)(wih_bf + g * DIN + qq * 8);
    int dst = g * 64 + ((qq ^ ((g >> 1) & 3)) << 4);
    *(bf16x8*)(wih_l + dst) = v;
  }

  // ---- zero h-part of buffer 0 and stage x(t=0) ----
  if (tid < 256) *(f32x4*)(zb + tid * 16) = f32x4{0.f, 0.f, 0.f, 0.f};

  const int xrow = tid >> 5, xd = tid & 31;          // for tid<256
  const int xoff = (32 + (xd >> 3)) * 128 + xrow * 16 + (xd & 7) * 2;
  const float* xq = x_dd + (size_t)(b0 + xrow) * DIN + xd;
  const bool xthr = tid < 256;
  if (xthr) *(unsigned short*)(zb + xoff) = f2bf(xq[0]);
  xq += (size_t)BTOT * DIN;                           // points at t=1

  // ---- Whh into registers, B-frag layout: wr[s][kk] = W[nt_s*16+m][kk*32+q*8..+7] ----
  bf16x8 wr[6][8];
  #pragma unroll
  for (int s = 0; s < 6; ++s) {
    const int nt = w + (s % 3) * 16 + (s >= 3 ? 8 : 0);
    const unsigned short* wp = whh_bf + (size_t)(nt * 16 + m) * HD + q * 8;
    #pragma unroll
    for (int kk = 0; kk < 8; ++kk) wr[s][kk] = *(const bf16x8*)(wp + kk * 32);
  }

  // ---- per-lane bias (folded into MFMA C-init) and static input gate ----
  const float bfv = bias[j], bgv = bias[HD + j], bov = bias[2 * HD + j];
  float cst[4], ig[4];
  #pragma unroll
  for (int r = 0; r < 4; ++r) {
    const int row = (q & 1) * 4 + r;
    float a = b_in[j];
    const float* xr = x_s + (size_t)(b0 + row) * SIN;
    const float* wn = w_in + (size_t)j * SIN;
    #pragma unroll
    for (int ss = 0; ss < SIN; ++ss) a += xr[ss] * wn[ss];
    ig[r] = fsig(a);
    cst[r] = 0.0f;
  }

  // ---- address bases ----
  const int abase  = q * 128 + (m & 7) * 16;                              // A-frag read
  const int wboff  = ((j >> 5) * 4 + ((j >> 3) & 3)) * 128 + (j & 7) * 2
                   + (q & 1) * 64;                                        // h write
  const int wibase = (w * 16 + m) * 64 + ((q ^ ((m >> 1) & 3)) << 4);     // Wih LDS read

  __syncthreads();

  for (int t = 0; t < TT; ++t) {
    const char* zc = zb + (t & 1) * ZBUF;          // read buffer
    char*       zn = zb + ((t & 1) ^ 1) * ZBUF;    // write buffer

    // prefetch x(t+1)
    float xv = 0.0f;
    if (xthr && t + 1 < TT) xv = xq[0];

    // ---- MFMA: gates = z @ W^T + bias ----
    f32x4 acc[6];
    #pragma unroll
    for (int s = 0; s < 6; ++s) {
      const float bv = (s % 3 == 0) ? bfv : (s % 3 == 1) ? bgv : bov;
      acc[s] = f32x4{bv, bv, bv, bv};
    }
    #pragma unroll
    for (int kk = 0; kk < 8; ++kk) {
      bf16x8 af = *(const bf16x8*)(zc + abase + kk * 512);
      #pragma unroll
      for (int s = 0; s < 6; ++s)
        acc[s] = __builtin_amdgcn_mfma_f32_16x16x32_bf16(af, wr[s][kk], acc[s], 0, 0, 0);
    }
    {   // x-part (kk=8)
      bf16x8 ax = *(const bf16x8*)(zc + abase + 8 * 512);
      bf16x8 wx0 = *(const bf16x8*)(wih_l + wibase);
      bf16x8 wx1 = *(const bf16x8*)(wih_l + wibase + 16384);
      bf16x8 wx2 = *(const bf16x8*)(wih_l + wibase + 32768);
      bf16x8 wx3 = *(const bf16x8*)(wih_l + wibase + 8192);
      bf16x8 wx4 = *(const bf16x8*)(wih_l + wibase + 24576);
      bf16x8 wx5 = *(const bf16x8*)(wih_l + wibase + 40960);
      acc[0] = __builtin_amdgcn_mfma_f32_16x16x32_bf16(ax, wx0, acc[0], 0, 0, 0);
      acc[1] = __builtin_amdgcn_mfma_f32_16x16x32_bf16(ax, wx1, acc[1], 0, 0, 0);
      acc[2] = __builtin_amdgcn_mfma_f32_16x16x32_bf16(ax, wx2, acc[2], 0, 0, 0);
      acc[3] = __builtin_amdgcn_mfma_f32_16x16x32_bf16(ax, wx3, acc[3], 0, 0, 0);
      acc[4] = __builtin_amdgcn_mfma_f32_16x16x32_bf16(ax, wx4, acc[4], 0, 0, 0);
      acc[5] = __builtin_amdgcn_mfma_f32_16x16x32_bf16(ax, wx5, acc[5], 0, 0, 0);
    }

    // ---- elementwise in registers (q<2 uses triple 0-2, q>=2 uses 3-5: D rows
    //      8-15 are exact duplicates of 0-7 because A rows 8-15 read h[m&7]) ----
    #pragma unroll
    for (int r = 0; r < 4; ++r) {
      float pf = (q < 2) ? acc[0][r] : acc[3][r];
      float pg = (q < 2) ? acc[1][r] : acc[4][r];
      float po = (q < 2) ? acc[2][r] : acc[5][r];
      float f = fsig(pf);
      float g = ftanh(pg);
      float o = fsig(po);
      float c = f * cst[r] + ig[r] * g;
      cst[r] = c;
      float h = o * ftanh(c);
      *(unsigned short*)(zn + wboff + r * 16) = f2bf(h);
    }

    // stage x(t+1) into next buffer
    if (xthr && t + 1 < TT) {
      *(unsigned short*)(zn + xoff) = f2bf(xv);
      xq += (size_t)BTOT * DIN;
    }
    __syncthreads();
  }

  // ---- output: out[b] = sum_j h[b][j] * w_dense[j] + b_dense[0] ----
  if (tid < 64) {
    const char* hb = zb + (TT & 1) * ZBUF;   // final h buffer (TT=365 -> buffer 1)
    int row = tid >> 3, seg = tid & 7;
    float sum = 0.0f;
    #pragma unroll
    for (int jj = 0; jj < 32; ++jj) {
      int off = ((seg * 4 + (jj >> 3)) * 8 + row) * 16 + (jj & 7) * 2;
      unsigned short hu = *(const unsigned short*)(hb + off);
      sum += bf2f(hu) * w_dense[seg * 32 + jj];
    }
    sum += __shfl_xor(sum, 1, 64);
    sum += __shfl_xor(sum, 2, 64);
    sum += __shfl_xor(sum, 4, 64);
    if ((tid & 7) == 0) out[b0 + row] = sum + b_dense[0];
  }
}

extern "C" void kernel_launch(void* const* d_in, const int* in_sizes, int n_in,
                              void* d_out, int out_size, void* d_ws, size_t ws_size,
                              hipStream_t stream) {
  (void)in_sizes; (void)n_in; (void)out_size; (void)ws_size;
  const float* x_dd = (const float*)d_in[0];
  const float* x_s  = (const float*)d_in[1];
  const float* wih  = (const float*)d_in[2];
  const float* whh  = (const float*)d_in[3];
  const float* bias = (const float*)d_in[4];
  const float* w_in = (const float*)d_in[5];
  const float* b_in = (const float*)d_in[6];
  const float* w_d  = (const float*)d_in[7];
  const float* b_d  = (const float*)d_in[8];
  float* out = (float*)d_out;

  unsigned short* whh_bf = (unsigned short*)d_ws;            // 768*256 bf16
  unsigned short* wih_bf = whh_bf + G3 * HD;                 // 768*32  bf16

  prep_kernel<<<128, 256, 0, stream>>>(whh, wih, whh_bf, wih_bf);
  ealstm_kernel<<<BTOT / BBLK, BLOCK, 0, stream>>>(
      x_dd, x_s, bias, w_in, b_in, w_d, b_d, whh_bf, wih_bf, out);
}